// Round 6
// baseline (494.785 us; speedup 1.0000x reference)
//
#include <hip/hip_runtime.h>

// ConvLSTM fused, MI355X (gfx950). T=16, B=4, C=32, H=W=64, HID=64.
// Round 14 = Round 13 resubmit + zero_ws fix (R13 never ran: container
// infra failure; audit also found I'd dropped the h-padding zeroing ->
// halo reads would hit poisoned workspace. Restored.)
//  Design: heterogeneous A/B blocks in one launch.
//  Per launch t: blocks 0-511 ("A") do h2h+LSTM for step t, acc seeded
//  from precomputed x2h gates xg(t); blocks 512-767 ("B") compute x2h
//  for step t+1 and write xg(t+1) in A's exact MFMA-fragment layout
//  (ping-pong). B has zero in-launch deps -> true phase diversity per CU
//  (3 blocks/CU, 52KB LDS each, 12 waves/CU): B's MFMA overlaps A's
//  h-stage drain + epilogue. 18 launches; kernel boundaries provide
//  cross-XCD visibility (R10: grid.sync ~80us/step - never again).
//  Fallback to verified fp32 kernel if ws too small.

#define TSTEPS 16
#define BATCH  4
#define CX     32
#define HID    64
#define HW     64
#define PW     66
#define QS     528     // shorts per q-slice row  = PW*8
#define XROW   2112    // shorts per x row  = 4*QS
#define HROW   4224    // shorts per h row  = 8*QS
#define LROW   1088    // shorts per staged LDS row segment = 4*34*8
#define SROWS  6       // A: staged h rows per block (4 outputs + 2 halo)
#define BROWS  10      // B: staged x rows per block (8 outputs + 2 halo)

typedef short bf16x8 __attribute__((ext_vector_type(8)));
typedef float f32x4  __attribute__((ext_vector_type(4)));
typedef unsigned short u16x4 __attribute__((ext_vector_type(4)));

__device__ __forceinline__ float sigmoidf_(float x){ return 1.0f/(1.0f+__expf(-x)); }
__device__ __forceinline__ float tanhf_(float x){ return 1.0f - 2.0f/(__expf(2.0f*x)+1.0f); }

__device__ __forceinline__ unsigned short f2bf(float f){
  unsigned u = __float_as_uint(f);
  return (unsigned short)((u + 0x7FFFu + ((u>>16)&1u)) >> 16);
}
__device__ __forceinline__ float bf2f(unsigned short s){ return __uint_as_float(((unsigned)s)<<16); }

__device__ __forceinline__ void gload_lds16(const void* g, void* l){
  __builtin_amdgcn_global_load_lds(
      (const __attribute__((address_space(1))) void*)g,
      (__attribute__((address_space(3))) void*)l, 16, 0, 0);
}

// xg fragment slot: 32 floats per (b, y, c2, lane), [g][ns][r] order.
__device__ __forceinline__ size_t xg_slot(int b, int y, int c2, int lane){
  return ((((size_t)b*64 + y)*8 + c2)*64 + lane)*32;
}

// ---------------- prep kernels (once per call) ----------------

// weights, block-contiguous tap slices in lane-contiguous order:
// wxT[(tap*4+chunk)*2048 + (g*64 + q*16 + h16)*8 + c8]            (q=c>>3)
// whT[(tap*4+chunk)*4096 + kc*2048 + (g*64 + q*16 + h16)*8 + c8]  (kc=c>>5)
__global__ __launch_bounds__(256) void prep_w(
    const float* __restrict__ wx, const float* __restrict__ wh,
    unsigned short* __restrict__ wxT, unsigned short* __restrict__ whT)
{
  int idx = blockIdx.x*256 + threadIdx.x;
  if (idx < 9*256*64){
    int tap = idx / (256*64);
    int rem = idx - tap*(256*64);
    int o = rem >> 6, c = rem & 63;
    int g = o >> 6, chunk = (o >> 4) & 3, h16 = o & 15;
    int kc = c >> 5, cc = c & 31, q = cc >> 3, c8 = cc & 7;
    whT[(size_t)(tap*4 + chunk)*4096 + kc*2048 + (g*64 + q*16 + h16)*8 + c8] =
        f2bf(wh[(o*HID + c)*9 + tap]);
  }
  if (idx < 9*256*32){
    int tap = idx / (256*32);
    int rem = idx - tap*(256*32);
    int o = rem >> 5, c = rem & 31;
    int g = o >> 6, chunk = (o >> 4) & 3, h16 = o & 15;
    int q = c >> 3, c8 = c & 7;
    wxT[(size_t)(tap*4 + chunk)*2048 + (g*64 + q*16 + h16)*8 + c8] =
        f2bf(wx[(o*CX + c)*9 + tap]);
  }
}

// x [T*B, CX, 64, 64] fp32 -> xT [T*B][yp 66][q 4][xp 66][c8 8] bf16 hi/lo
__global__ __launch_bounds__(256) void prep_x(
    const float* __restrict__ x,
    unsigned short* __restrict__ xh, unsigned short* __restrict__ xl)
{
  __shared__ float tile[CX][HW];
  const int tb = blockIdx.x, yp = blockIdx.y, tid = threadIdx.x;
  const int y = yp - 1;
  const bool rowok = (y >= 0 && y < HW);
  if (rowok){
    const float* src = x + (size_t)tb*CX*HW*HW + y*HW;
    for (int i = tid; i < CX*HW; i += 256){
      int c = i >> 6, xc = i & 63;
      tile[c][xc] = src[(size_t)c*HW*HW + xc];
    }
  }
  __syncthreads();
  size_t base = ((size_t)tb*PW + yp)*XROW;
  for (int i = tid; i < PW*CX; i += 256){
    int xp = i >> 5, c = i & 31;
    int xg = xp - 1;
    float v = (rowok && xg >= 0 && xg < HW) ? tile[c][xg] : 0.f;
    unsigned short h = f2bf(v);
    size_t o = base + ((size_t)(c >> 3)*PW + xp)*8 + (c & 7);
    xh[o] = h;
    xl[o] = f2bf(v - bf2f(h));
  }
}

__global__ __launch_bounds__(256) void zero_ws(unsigned long long* p, size_t n64){
  size_t i = (size_t)blockIdx.x*256 + threadIdx.x;
  size_t stride = (size_t)gridDim.x*256;
  for (; i < n64; i += stride) p[i] = 0ull;
}

// ---------------- fused A/B step kernel ----------------
// grid 768 x 256 thr (4 waves), LDS 52224B -> 3 blocks/CU (12 waves/CU).
// A (blocks 0..511): (c2=bid>>6, ys16=(bid&63)>>2, b=bid&3); 4-row slab.
//   h2h conv (acc seeded from xg) + LSTM + h/hc writes.
// B (blocks 512..767): (c2=j>>5, ys8=(j&31)>>2, b=j&3); 8-row slab,
//   wave w rows {2w, 2w+1}; x2h conv for step tB -> xg write.
// flags: 1=doA, 2=firstA(no h2h), 4=doB, 8=writeH(hc buffers).

#define MFMA(a,b,c) __builtin_amdgcn_mfma_f32_16x16x32_bf16((a),(b),(c),0,0,0)

__global__ __launch_bounds__(256, 3) void fused_step(
    const unsigned short* __restrict__ xTh, const unsigned short* __restrict__ xTl,
    const unsigned short* __restrict__ wxT, const unsigned short* __restrict__ whT,
    const unsigned short* __restrict__ hph, const unsigned short* __restrict__ hpl,
    unsigned short* __restrict__ hch, unsigned short* __restrict__ hcl,
    const float* __restrict__ bxb, const float* __restrict__ bhb,
    float* __restrict__ c_state,   // [512 blk][256 tid][2 ns][4 r] fp32
    float* __restrict__ h_out,     // [B][HID][64][64] fp32 (d_out slice t)
    const float* __restrict__ xgR, // xg(t)  read by A
    float* __restrict__ xgW,       // xg(tB) written by B
    int tB, int flags)
{
  __shared__ __attribute__((aligned(16))) short sbuf[26112];  // 52224 B

  const int tid  = threadIdx.x;       // 0..255
  const int lane = tid & 63;
  const int w    = tid >> 6;          // wave 0..3
  const int nn = lane & 15, q = lane >> 4;
  const int wfo = (q*16 + nn)*8;      // weight fragment offset (shorts)
  const int bid = blockIdx.x;

  if (bid < 512){
    // ================= A: h2h + LSTM for step t =================
    if (!(flags & 1)) return;
    const bool first = (flags & 2) != 0;
    const int c2 = bid >> 6, rem = bid & 63;
    const int ys = rem >> 2, b = rem & 3;
    const int chunk = c2 >> 1, xh = c2 & 1;
    const int y0 = ys*4, y = y0 + w, m0 = chunk*16;
    const size_t cslot = ((size_t)bid*256 + tid)*8;

    // ---- async stage h rows (dest linear = i*16B) ----
    if (!first){
      const size_t hbase = ((size_t)b*PW + y0)*HROW;
#pragma unroll 1
      for (int i = tid; i < 2*SROWS*8*34; i += 256){
        const int px = i % 34;
        const int j  = i / 34;
        const int kcq = j & 7;
        const int r2  = j >> 3;
        const int r   = r2 % SROWS;
        const int kind = r2 / SROWS;
        const unsigned short* src = (kind ? hpl : hph)
            + hbase + (size_t)r*HROW + kcq*QS + (xh*32 + px)*8;
        gload_lds16(src, &sbuf[(size_t)i*8]);
      }
    }

    // ---- acc init from xg(t): 128B contiguous per lane ----
    f32x4 acc[4][2];
    {
      const float* xr = xgR + xg_slot(b, y, c2, lane);
#pragma unroll
      for (int g = 0; g < 4; ++g)
#pragma unroll
        for (int ns = 0; ns < 2; ++ns)
          acc[g][ns] = *(const f32x4*)&xr[g*8 + ns*4];
    }

    // ---- early c read ----
    f32x4 cpre[2];
    if (!first){
      cpre[0] = *(const f32x4*)&c_state[cslot];
      cpre[1] = *(const f32x4*)&c_state[cslot + 4];
    } else {
      cpre[0] = (f32x4){0.f,0.f,0.f,0.f};
      cpre[1] = (f32x4){0.f,0.f,0.f,0.f};
    }

    auto loadwh = [&](int tap, bf16x8 (&ah)[2][4]){
      const unsigned short* hp = whT + (size_t)(tap*4 + chunk)*4096 + wfo;
#pragma unroll
      for (int kc = 0; kc < 2; ++kc)
#pragma unroll
        for (int g = 0; g < 4; ++g) ah[kc][g] = *(const bf16x8*)(hp + kc*2048 + g*512);
    };
    auto bodyA = [&](int tap, const bf16x8 (&ah)[2][4]){
      const int ky = tap / 3;
      const int kx = tap - ky*3;
      const int r0 = w + ky;            // staged row index 0..5
      const int ps = kx + nn;
      bf16x8 bhf[2][2][2];   // [kind][kc][ns]
#pragma unroll
      for (int kc = 0; kc < 2; ++kc)
#pragma unroll
        for (int ns = 0; ns < 2; ++ns){
          const int o = (q*34 + ns*16 + ps)*8;
          bhf[0][kc][ns] = *(const bf16x8*)&sbuf[(r0*2 + kc)*LROW + o];
          bhf[1][kc][ns] = *(const bf16x8*)&sbuf[(((SROWS + r0)*2) + kc)*LROW + o];
        }
      __builtin_amdgcn_s_setprio(1);
#pragma unroll
      for (int kc = 0; kc < 2; ++kc)
#pragma unroll
        for (int ns = 0; ns < 2; ++ns)
#pragma unroll
          for (int g = 0; g < 4; ++g){
            acc[g][ns] = MFMA(ah[kc][g], bhf[0][kc][ns], acc[g][ns]);
            acc[g][ns] = MFMA(ah[kc][g], bhf[1][kc][ns], acc[g][ns]);
          }
      __builtin_amdgcn_s_setprio(0);
    };

    bf16x8 ahA[2][4], ahB[2][4];
    if (!first){ loadwh(0, ahA); loadwh(1, ahB); }

    __syncthreads();   // drains vmcnt(0): h staging + xg + c + weights

    if (!first){
#pragma unroll 1
      for (int tp = 0; tp < 8; tp += 2){
        bodyA(tp, ahA);
        loadwh(tp+2, ahA);
        bodyA(tp+1, ahB);
        if (tp < 6) loadwh(tp+3, ahB);
      }
      bodyA(8, ahA);
    }

    // ---- epilogue: LSTM, c register-local ----
    f32x4 bv[4];
#pragma unroll
    for (int g = 0; g < 4; ++g){
      f32x4 ba = *(const f32x4*)&bxb[g*HID + m0 + 4*q];
      f32x4 bb = *(const f32x4*)&bhb[g*HID + m0 + 4*q];
      bv[g] = ba + bb;
    }
    const int kc  = chunk >> 1;
    const int qh  = ((chunk & 1) << 1) | (q >> 1);
    const int c8b = (q & 1) * 4;
#pragma unroll
    for (int ns = 0; ns < 2; ++ns){
      const int xg = xh*32 + ns*16 + nn;
      f32x4 cn;
      float hn[4];
#pragma unroll
      for (int r = 0; r < 4; ++r){
        float iv = sigmoidf_(acc[0][ns][r] + bv[0][r]);
        float fv = sigmoidf_(acc[1][ns][r] + bv[1][r]);
        float gv = tanhf_  (acc[2][ns][r] + bv[2][r]);
        float ov = sigmoidf_(acc[3][ns][r] + bv[3][r]);
        float cnv = fv*cpre[ns][r] + iv*gv;
        cn[r] = cnv;
        hn[r] = ov * tanhf_(cnv);
      }
      *(f32x4*)&c_state[cslot + ns*4] = cn;
#pragma unroll
      for (int r = 0; r < 4; ++r)
        h_out[(((size_t)b*HID + m0 + 4*q + r)*HW + y)*HW + xg] = hn[r];
      if (flags & 8){
        const size_t hoff = ((size_t)b*PW + (y+1))*HROW + (kc*4 + qh)*QS + (xg+1)*8 + c8b;
        u16x4 ph, pl;
#pragma unroll
        for (int r = 0; r < 4; ++r){
          unsigned short h = f2bf(hn[r]);
          ph[r] = h;
          pl[r] = f2bf(hn[r] - bf2f(h));
        }
        *(u16x4*)&hch[hoff] = ph;
        *(u16x4*)&hcl[hoff] = pl;
      }
    }
  } else {
    // ================= B: x2h for step tB -> xg =================
    if (!(flags & 4)) return;
    const int j = bid - 512;
    const int c2 = j >> 5, rem = j & 31;
    const int ys8 = rem >> 2, b = rem & 3;
    const int chunk = c2 >> 1, xh = c2 & 1;
    const int y0B = ys8*8;
    const int tb = tB*BATCH + b;

    // ---- async stage x rows (dest linear = i*16B) ----
    {
      const size_t xbase = ((size_t)tb*PW + y0B)*XROW;
#pragma unroll 1
      for (int i = tid; i < 2*BROWS*4*34; i += 256){
        const int px = i % 34;
        const int jj = i / 34;
        const int qq = jj & 3;
        const int r2 = jj >> 2;
        const int r  = r2 % BROWS;
        const int kind = r2 / BROWS;
        const unsigned short* src = (kind ? xTl : xTh)
            + xbase + (size_t)r*XROW + qq*QS + (xh*32 + px)*8;
        gload_lds16(src, &sbuf[(size_t)i*8]);
      }
    }

    auto loadwx = [&](int tap, bf16x8 (&ax)[4]){
      const unsigned short* wp = wxT + (size_t)(tap*4 + chunk)*2048 + wfo;
#pragma unroll
      for (int g = 0; g < 4; ++g) ax[g] = *(const bf16x8*)(wp + g*512);
    };

    __syncthreads();   // x staged

#pragma unroll 1
    for (int rr = 0; rr < 2; ++rr){
      const int rowb = 2*w + rr;        // output row within 8-row slab
      f32x4 acc[4][2];
#pragma unroll
      for (int g = 0; g < 4; ++g)
#pragma unroll
        for (int ns = 0; ns < 2; ++ns)
          acc[g][ns] = (f32x4){0.f,0.f,0.f,0.f};

      auto bodyB = [&](int tap, const bf16x8 (&ax)[4]){
        const int ky = tap / 3;
        const int kx = tap - ky*3;
        const int r0 = rowb + ky;       // staged row 0..9
        const int ps = kx + nn;
        bf16x8 bxf[2][2];
#pragma unroll
        for (int ns = 0; ns < 2; ++ns){
          const int o = (q*34 + ns*16 + ps)*8;
          bxf[0][ns] = *(const bf16x8*)&sbuf[r0*LROW + o];
          bxf[1][ns] = *(const bf16x8*)&sbuf[(BROWS + r0)*LROW + o];
        }
        __builtin_amdgcn_s_setprio(1);
#pragma unroll
        for (int ns = 0; ns < 2; ++ns)
#pragma unroll
          for (int g = 0; g < 4; ++g){
            acc[g][ns] = MFMA(ax[g], bxf[0][ns], acc[g][ns]);
            acc[g][ns] = MFMA(ax[g], bxf[1][ns], acc[g][ns]);
          }
        __builtin_amdgcn_s_setprio(0);
      };

      bf16x8 axA[4], axB[4];
      loadwx(0, axA); loadwx(1, axB);
#pragma unroll 1
      for (int tp = 0; tp < 8; tp += 2){
        bodyB(tp, axA);
        loadwx(tp+2, axA);
        bodyB(tp+1, axB);
        if (tp < 6) loadwx(tp+3, axB);
      }
      bodyB(8, axA);

      float* xw = xgW + xg_slot(b, y0B + rowb, c2, lane);
#pragma unroll
      for (int g = 0; g < 4; ++g)
#pragma unroll
        for (int ns = 0; ns < 2; ++ns)
          *(f32x4*)&xw[g*8 + ns*4] = acc[g][ns];
    }
  }
}

// ---------------- fallback: fp32 kernel (verified round 3) ----------------

#define FCHUNK  8
#define FTILE_H 16
#define FROWS   (FTILE_H + 2)
#define FSTRIDE 68

__device__ __forceinline__ void do_chunk_f(
    float tile[FCHUNK][FROWS][FSTRIDE],
    const float* __restrict__ src,
    const float* __restrict__ wp0, const float* __restrict__ wp1,
    const float* __restrict__ wp2, const float* __restrict__ wp3,
    int gy0, int txg, int ty, int tid, float (&acc)[4][2][4])
{
  __syncthreads();
  for (int s = tid; s < FCHUNK * FROWS * 32; s += 128) {
    int c2 = s & 31;
    int rowid = s >> 5;
    int ic = rowid / FROWS;
    int r  = rowid - ic * FROWS;
    int gy = gy0 - 1 + r;
    if ((unsigned)gy < (unsigned)HW) {
      float2 v = *(const float2*)&src[(ic << 12) + (gy << 6) + (c2 << 1)];
      *(float2*)&tile[ic][r][2 + (c2 << 1)] = v;
    }
  }
  __syncthreads();
  for (int ic = 0; ic < FCHUNK; ++ic) {
    float w0[9], w1[9], w2[9], w3[9];
#pragma unroll
    for (int k = 0; k < 9; ++k) {
      w0[k] = wp0[ic*9+k]; w1[k] = wp1[ic*9+k];
      w2[k] = wp2[ic*9+k]; w3[k] = wp3[ic*9+k];
    }
    float rv[4][8];
#pragma unroll
    for (int rr = 0; rr < 4; ++rr) {
      const float* p = &tile[ic][2*ty+rr][4*txg];
      float4 a  = *(const float4*)p;
      float4 bb = *(const float4*)(p + 4);
      rv[rr][0]=a.x; rv[rr][1]=a.y; rv[rr][2]=a.z; rv[rr][3]=a.w;
      rv[rr][4]=bb.x; rv[rr][5]=bb.y; rv[rr][6]=bb.z; rv[rr][7]=bb.w;
    }
#pragma unroll
    for (int j = 0; j < 2; ++j)
#pragma unroll
      for (int dy = 0; dy < 3; ++dy)
#pragma unroll
        for (int qq = 0; qq < 4; ++qq)
#pragma unroll
          for (int dx = 0; dx < 3; ++dx) {
            float v = rv[j+dy][qq+dx+1];
            int k = dy*3+dx;
            acc[0][j][qq] = fmaf(v, w0[k], acc[0][j][qq]);
            acc[1][j][qq] = fmaf(v, w1[k], acc[1][j][qq]);
            acc[2][j][qq] = fmaf(v, w2[k], acc[2][j][qq]);
            acc[3][j][qq] = fmaf(v, w3[k], acc[3][j][qq]);
          }
  }
}

__global__ __launch_bounds__(128) void convlstm_step_f(
    const float* __restrict__ x_t, const float* __restrict__ h_prev,
    const float* __restrict__ w_x2h, const float* __restrict__ b_x2h,
    const float* __restrict__ w_h2h, const float* __restrict__ b_h2h,
    float* __restrict__ c_state, float* __restrict__ h_out, int first)
{
  __shared__ float tile[FCHUNK][FROWS][FSTRIDE];
  const int txg = threadIdx.x, ty = threadIdx.y;
  const int tid = ty*16 + txg;
  const int by = blockIdx.x, hc = blockIdx.y, b = blockIdx.z;
  const int gy0 = by * FTILE_H;
  {
    float2* p = (float2*)&tile[0][0][0];
    for (int i = tid; i < FCHUNK*FROWS*FSTRIDE/2; i += 128)
      p[i] = make_float2(0.f, 0.f);
  }
  float acc[4][2][4];
#pragma unroll
  for (int g = 0; g < 4; ++g)
#pragma unroll
    for (int j = 0; j < 2; ++j)
#pragma unroll
      for (int qq = 0; qq < 4; ++qq) acc[g][j][qq] = 0.f;
  {
    const float* wx0 = w_x2h + (size_t)(0*HID+hc)*CX*9;
    const float* wx1 = w_x2h + (size_t)(1*HID+hc)*CX*9;
    const float* wx2 = w_x2h + (size_t)(2*HID+hc)*CX*9;
    const float* wx3 = w_x2h + (size_t)(3*HID+hc)*CX*9;
    for (int c0 = 0; c0 < CX; c0 += FCHUNK)
      do_chunk_f(tile, x_t + ((size_t)(b*CX+c0) << 12),
                 wx0+c0*9, wx1+c0*9, wx2+c0*9, wx3+c0*9, gy0, txg, ty, tid, acc);
  }
  if (!first){
    const float* wh0 = w_h2h + (size_t)(0*HID+hc)*HID*9;
    const float* wh1 = w_h2h + (size_t)(1*HID+hc)*HID*9;
    const float* wh2 = w_h2h + (size_t)(2*HID+hc)*HID*9;
    const float* wh3 = w_h2h + (size_t)(3*HID+hc)*HID*9;
    for (int c0 = 0; c0 < HID; c0 += FCHUNK)
      do_chunk_f(tile, h_prev + ((size_t)(b*HID+c0) << 12),
                 wh0+c0*9, wh1+c0*9, wh2+c0*9, wh3+c0*9, gy0, txg, ty, tid, acc);
  }
  const float bi = b_x2h[0*HID+hc] + b_h2h[0*HID+hc];
  const float bf = b_x2h[1*HID+hc] + b_h2h[1*HID+hc];
  const float bg = b_x2h[2*HID+hc] + b_h2h[2*HID+hc];
  const float bo = b_x2h[3*HID+hc] + b_h2h[3*HID+hc];
#pragma unroll
  for (int j = 0; j < 2; ++j){
    const int row = gy0 + 2*ty + j;
    const int off = ((b*HID + hc)*HW + row)*HW + 4*txg;
    float4 cpv4 = make_float4(0.f,0.f,0.f,0.f);
    if (!first) cpv4 = *(const float4*)&c_state[off];
    float cn[4], hn[4];
    const float cpv[4] = {cpv4.x, cpv4.y, cpv4.z, cpv4.w};
#pragma unroll
    for (int qq = 0; qq < 4; ++qq){
      const float ig = sigmoidf_(acc[0][j][qq] + bi);
      const float fg = sigmoidf_(acc[1][j][qq] + bf);
      const float gg = tanhf_  (acc[2][j][qq] + bg);
      const float og = sigmoidf_(acc[3][j][qq] + bo);
      const float cnv = fg*cpv[qq] + ig*gg;
      cn[qq] = cnv;
      hn[qq] = og * tanhf_(cnv);
    }
    *(float4*)&c_state[off] = make_float4(cn[0],cn[1],cn[2],cn[3]);
    *(float4*)&h_out[off]   = make_float4(hn[0],hn[1],hn[2],hn[3]);
  }
}

// ---------------- launcher ----------------

extern "C" void kernel_launch(void* const* d_in, const int* in_sizes, int n_in,
                              void* d_out, int out_size, void* d_ws, size_t ws_size,
                              hipStream_t stream) {
  const float* x     = (const float*)d_in[0];
  const float* w_x2h = (const float*)d_in[1];
  const float* b_x2h = (const float*)d_in[2];
  const float* w_h2h = (const float*)d_in[3];
  const float* b_h2h = (const float*)d_in[4];
  float* out = (float*)d_out;

  // ws layout (256-aligned)
  size_t off = 0;
  auto alloc = [&](size_t bytes) -> char* {
    char* p = (char*)d_ws + off;
    off += (bytes + 255) & ~(size_t)255;
    return p;
  };
  float* c_state = (float*)alloc((size_t)512*256*8*4);                // 4 MB
  unsigned short* wxT = (unsigned short*)alloc((size_t)9*4*2048*2);   // 147 KB
  unsigned short* whT = (unsigned short*)alloc((size_t)9*4*4096*2);   // 295 KB
  const size_t hT_bytes = (size_t)BATCH*PW*HROW*2;                    // 2,230,272
  unsigned short* hA_hi = (unsigned short*)alloc(hT_bytes);
  unsigned short* hA_lo = (unsigned short*)alloc(hT_bytes);
  unsigned short* hB_hi = (unsigned short*)alloc(hT_bytes);
  unsigned short* hB_lo = (unsigned short*)alloc(hT_bytes);
  const size_t xT_bytes = (size_t)TSTEPS*BATCH*PW*XROW*2;             // 17,842,176
  unsigned short* xT_hi = (unsigned short*)alloc(xT_bytes);
  unsigned short* xT_lo = (unsigned short*)alloc(xT_bytes);
  const size_t xg_bytes = (size_t)4*64*8*64*32*4;                     // 16 MB
  float* xg0 = (float*)alloc(xg_bytes);
  float* xg1 = (float*)alloc(xg_bytes);
  const size_t need = off;

  const size_t x_step = (size_t)BATCH*CX*HW*HW;
  const size_t h_step = (size_t)BATCH*HID*HW*HW;

  if (need <= ws_size) {
    // ---- MFMA A/B path ----
    prep_w<<<(9*256*HID + 255)/256, 256, 0, stream>>>(w_x2h, w_h2h, wxT, whT);
    prep_x<<<dim3(TSTEPS*BATCH, PW), 256, 0, stream>>>(x, xT_hi, xT_lo);
    zero_ws<<<1024, 256, 0, stream>>>((unsigned long long*)hA_hi, 4*hT_bytes/8);

    // prologue: B-only, computes xg(0)
    fused_step<<<768, 256, 0, stream>>>(
        xT_hi, xT_lo, wxT, whT, hA_hi, hA_lo, hB_hi, hB_lo,
        b_x2h, b_h2h, c_state, out, xg1, xg0, 0, /*flags=*/4);

    for (int t = 0; t < TSTEPS; ++t) {
      unsigned short* hp_hi = (t & 1) ? hA_hi : hB_hi;
      unsigned short* hp_lo = (t & 1) ? hA_lo : hB_lo;
      unsigned short* hc_hi = (t & 1) ? hB_hi : hA_hi;
      unsigned short* hc_lo = (t & 1) ? hB_lo : hA_lo;
      const float* xgR = (t & 1) ? xg1 : xg0;
      float* xgW       = (t & 1) ? xg0 : xg1;
      int flags = 1 | (t == 0 ? 2 : 0) | (t < TSTEPS-1 ? (4 | 8) : 0);
      fused_step<<<768, 256, 0, stream>>>(
          xT_hi, xT_lo, wxT, whT, hp_hi, hp_lo, hc_hi, hc_lo,
          b_x2h, b_h2h, c_state, out + (size_t)t*h_step,
          xgR, xgW, t + 1, flags);
    }
  } else {
    // ---- fallback fp32 path ----
    dim3 grid(HW / FTILE_H, HID, BATCH);
    dim3 block(16, 8);
    for (int t = 0; t < TSTEPS; ++t) {
      const float* x_t    = x + (size_t)t*x_step;
      const float* h_prev = (t == 0) ? x : out + (size_t)(t-1)*h_step;
      float* h_out        = out + (size_t)t*h_step;
      convlstm_step_f<<<grid, block, 0, stream>>>(
          x_t, h_prev, w_x2h, b_x2h, w_h2h, b_h2h, c_state, h_out, t == 0 ? 1 : 0);
    }
  }
}

// Round 7
// 417.348 us; speedup vs baseline: 1.1855x; 1.1855x over previous
//
#include <hip/hip_runtime.h>

// ConvLSTM fused, MI355X (gfx950). T=16, B=4, C=32, H=W=64, HID=64.
// Round 15: revert R14's A/B split (494us, xg traffic + no overlap win).
// Base = R12 (420.7us verified: 2 blocks/CU, 4-wave, async global_load_lds
// staging, private c layout, early c read, setprio, combined bias) plus:
//  - fully-unrolled 9-tap loop with cross-tap LDS-fragment double-buffer:
//    next tap's 12 ds_read_b128 issue before current tap's 48 MFMAs
//    (R10 counters: MFMA busy 5.6us/step vs 1.75us issue floor = 3x
//    stretch from at-use LDS reads). Weight sets 2-ahead as before, each
//    set overwritten only after its last use.
//  - strength-reduced staging decode: incremental px/j carry chain
//    replaces per-iter /34 %34 magic-mul (VALUBusy ~6us/step observed).
// Fallback to verified fp32 kernel if ws_size too small.

#define TSTEPS 16
#define BATCH  4
#define CX     32
#define HID    64
#define HW     64
#define PW     66
#define QS     528     // shorts per q-slice row  = PW*8
#define XROW   2112    // shorts per x row  = 4*QS
#define HROW   4224    // shorts per h row  = 8*QS
#define LROW   1088    // shorts per staged LDS row segment = 4*34*8
#define SROWS  6       // staged rows per block (4 outputs + 2 halo)

typedef short bf16x8 __attribute__((ext_vector_type(8)));
typedef float f32x4  __attribute__((ext_vector_type(4)));
typedef unsigned short u16x4 __attribute__((ext_vector_type(4)));

__device__ __forceinline__ float sigmoidf_(float x){ return 1.0f/(1.0f+__expf(-x)); }
__device__ __forceinline__ float tanhf_(float x){ return 1.0f - 2.0f/(__expf(2.0f*x)+1.0f); }

__device__ __forceinline__ unsigned short f2bf(float f){
  unsigned u = __float_as_uint(f);
  return (unsigned short)((u + 0x7FFFu + ((u>>16)&1u)) >> 16);
}
__device__ __forceinline__ float bf2f(unsigned short s){ return __uint_as_float(((unsigned)s)<<16); }

__device__ __forceinline__ void gload_lds16(const void* g, void* l){
  __builtin_amdgcn_global_load_lds(
      (const __attribute__((address_space(1))) void*)g,
      (__attribute__((address_space(3))) void*)l, 16, 0, 0);
}

// ---------------- prep kernels (once per call) ----------------

// weights, block-contiguous tap slices in lane-contiguous order:
// wxT[(tap*4+chunk)*2048 + (g*64 + q*16 + h16)*8 + c8]            (q=c>>3)
// whT[(tap*4+chunk)*4096 + kc*2048 + (g*64 + q*16 + h16)*8 + c8]  (kc=c>>5)
__global__ __launch_bounds__(256) void prep_w(
    const float* __restrict__ wx, const float* __restrict__ wh,
    unsigned short* __restrict__ wxT, unsigned short* __restrict__ whT)
{
  int idx = blockIdx.x*256 + threadIdx.x;
  if (idx < 9*256*64){
    int tap = idx / (256*64);
    int rem = idx - tap*(256*64);
    int o = rem >> 6, c = rem & 63;
    int g = o >> 6, chunk = (o >> 4) & 3, h16 = o & 15;
    int kc = c >> 5, cc = c & 31, q = cc >> 3, c8 = cc & 7;
    whT[(size_t)(tap*4 + chunk)*4096 + kc*2048 + (g*64 + q*16 + h16)*8 + c8] =
        f2bf(wh[(o*HID + c)*9 + tap]);
  }
  if (idx < 9*256*32){
    int tap = idx / (256*32);
    int rem = idx - tap*(256*32);
    int o = rem >> 5, c = rem & 31;
    int g = o >> 6, chunk = (o >> 4) & 3, h16 = o & 15;
    int q = c >> 3, c8 = c & 7;
    wxT[(size_t)(tap*4 + chunk)*2048 + (g*64 + q*16 + h16)*8 + c8] =
        f2bf(wx[(o*CX + c)*9 + tap]);
  }
}

// x [T*B, CX, 64, 64] fp32 -> xT [T*B][yp 66][q 4][xp 66][c8 8] bf16 hi/lo
__global__ __launch_bounds__(256) void prep_x(
    const float* __restrict__ x,
    unsigned short* __restrict__ xh, unsigned short* __restrict__ xl)
{
  __shared__ float tile[CX][HW];
  const int tb = blockIdx.x, yp = blockIdx.y, tid = threadIdx.x;
  const int y = yp - 1;
  const bool rowok = (y >= 0 && y < HW);
  if (rowok){
    const float* src = x + (size_t)tb*CX*HW*HW + y*HW;
    for (int i = tid; i < CX*HW; i += 256){
      int c = i >> 6, xc = i & 63;
      tile[c][xc] = src[(size_t)c*HW*HW + xc];
    }
  }
  __syncthreads();
  size_t base = ((size_t)tb*PW + yp)*XROW;
  for (int i = tid; i < PW*CX; i += 256){
    int xp = i >> 5, c = i & 31;
    int xg = xp - 1;
    float v = (rowok && xg >= 0 && xg < HW) ? tile[c][xg] : 0.f;
    unsigned short h = f2bf(v);
    size_t o = base + ((size_t)(c >> 3)*PW + xp)*8 + (c & 7);
    xh[o] = h;
    xl[o] = f2bf(v - bf2f(h));
  }
}

__global__ __launch_bounds__(256) void zero_ws(unsigned long long* p, size_t n64){
  size_t i = (size_t)blockIdx.x*256 + threadIdx.x;
  size_t stride = (size_t)gridDim.x*256;
  for (; i < n64; i += stride) p[i] = 0ull;
}

// ---------------- the MFMA step kernel ----------------
// grid (8 = chunk*2+xh, 16 = yslab, 4 = b) = 512 blocks; block 256 thr = 4 waves.
// wave w handles y = yslab*4 + w; wave tile M=64 (4g x 16hid) x N=32 px.
// h layout (global): [b][yp 66][kcq 8][xp 66][c8 8] bf16 hi/lo.
// LDS: xs[kind 2][r 6][q 4][px 34][c8 8], hs[kind 2][r 6][kc 2][q 4][px 34][8]
// (both linear in the staging loop index -> global_load_lds legal).
// c_state: private layout [block 512][tid 256][ns 2][r 4] fp32 (lane-linear).

#define MFMA(a,b,c) __builtin_amdgcn_mfma_f32_16x16x32_bf16((a),(b),(c),0,0,0)

template<int FIRST>
__global__ __launch_bounds__(256, 2) void step_mfma(
    const unsigned short* __restrict__ xTh, const unsigned short* __restrict__ xTl,
    const unsigned short* __restrict__ wxT, const unsigned short* __restrict__ whT,
    const unsigned short* __restrict__ hph, const unsigned short* __restrict__ hpl,
    unsigned short* __restrict__ hch, unsigned short* __restrict__ hcl,
    const float* __restrict__ bxb, const float* __restrict__ bhb,
    float* __restrict__ c_state,   // [512 blk][256 tid][2 ns][4 r] fp32
    float* __restrict__ h_out,     // [B][HID][64][64] fp32 (d_out slice t)
    int t)
{
  __shared__ __attribute__((aligned(16))) short xs[2*SROWS*LROW];   // 25.5 KB
  __shared__ __attribute__((aligned(16))) short hs[2*2*SROWS*LROW]; // 51 KB

  const int tid  = threadIdx.x;       // 0..255
  const int lane = tid & 63;
  const int w    = tid >> 6;          // wave 0..3
  const int nn = lane & 15, q = lane >> 4;
  const int chunk = blockIdx.x >> 1, xh = blockIdx.x & 1;
  const int y0 = blockIdx.y * 4;
  const int b  = blockIdx.z;
  const int m0 = chunk * 16;
  const int y  = y0 + w;
  const int tb = t*BATCH + b;
  const int wfo = (q*16 + nn)*8;      // weight fragment offset (shorts)

  // lane-linear private c slot: 8 floats (32B) per thread
  const size_t cslot =
      (((size_t)((blockIdx.z*16 + blockIdx.y)*8 + blockIdx.x))*256 + tid)*8;

  // ---- async stage x/h rows: LDS dest linear = i*16B; incremental decode ----
  {
    const size_t xbase = ((size_t)tb*PW + y0)*XROW;
    int px = tid % 34, j = tid / 34;            // i = j*34 + px invariant
#pragma unroll 1
    for (int i = tid; i < 2*SROWS*4*34; i += 256){
      const int qq = j & 3;
      const int r2 = j >> 2;
      const int kind = (r2 >= SROWS) ? 1 : 0;
      const int r  = r2 - kind*SROWS;
      const unsigned short* src = (kind ? xTl : xTh)
          + xbase + (size_t)r*XROW + qq*QS + (xh*32 + px)*8;
      gload_lds16(src, &xs[(size_t)i*8]);
      px += 18; j += 7; if (px >= 34){ px -= 34; ++j; }   // += 256 = 7*34+18
    }
  }
  if (!FIRST){
    const size_t hbase = ((size_t)b*PW + y0)*HROW;
    int px = tid % 34, j = tid / 34;
#pragma unroll 1
    for (int i = tid; i < 2*SROWS*8*34; i += 256){
      const int kcq = j & 7;
      const int r2  = j >> 3;
      const int kind = (r2 >= SROWS) ? 1 : 0;
      const int r  = r2 - kind*SROWS;
      const unsigned short* src = (kind ? hpl : hph)
          + hbase + (size_t)r*HROW + kcq*QS + (xh*32 + px)*8;
      gload_lds16(src, &hs[(size_t)i*8]);
      px += 18; j += 7; if (px >= 34){ px -= 34; ++j; }
    }
  }

  // ---- early c read: latency hides under the tap loop ----
  f32x4 cpre[2];
  if (!FIRST){
    cpre[0] = *(const f32x4*)&c_state[cslot];
    cpre[1] = *(const f32x4*)&c_state[cslot + 4];
  } else {
    cpre[0] = (f32x4){0.f,0.f,0.f,0.f};
    cpre[1] = (f32x4){0.f,0.f,0.f,0.f};
  }

  f32x4 acc[4][2];
#pragma unroll
  for (int g = 0; g < 4; ++g)
#pragma unroll
    for (int ns = 0; ns < 2; ++ns)
      acc[g][ns] = (f32x4){0.f, 0.f, 0.f, 0.f};

  // ---- loaders (weights: global/L1; fragments: LDS) ----
  auto loadwx = [&](int tap, bf16x8 (&ax)[4]){
    const unsigned short* wp = wxT + (size_t)(tap*4 + chunk)*2048 + wfo;
#pragma unroll
    for (int g = 0; g < 4; ++g) ax[g] = *(const bf16x8*)(wp + g*512);
  };
  auto loadwh = [&](int tap, bf16x8 (&ah)[2][4]){
    const unsigned short* hp = whT + (size_t)(tap*4 + chunk)*4096 + wfo;
#pragma unroll
    for (int kc = 0; kc < 2; ++kc)
#pragma unroll
      for (int g = 0; g < 4; ++g) ah[kc][g] = *(const bf16x8*)(hp + kc*2048 + g*512);
  };
  auto ldx = [&](int tap, bf16x8 (&bx)[2][2]){
    const int ky = tap/3, kx = tap - ky*3;
    const int r0 = w + ky, ps = kx + nn;
#pragma unroll
    for (int ns = 0; ns < 2; ++ns){
      const int o = (q*34 + ns*16 + ps)*8;
      bx[0][ns] = *(const bf16x8*)&xs[r0*LROW + o];
      bx[1][ns] = *(const bf16x8*)&xs[(SROWS + r0)*LROW + o];
    }
  };
  auto ldh = [&](int tap, bf16x8 (&bh)[2][2][2]){
    const int ky = tap/3, kx = tap - ky*3;
    const int r0 = w + ky, ps = kx + nn;
#pragma unroll
    for (int kc = 0; kc < 2; ++kc)
#pragma unroll
      for (int ns = 0; ns < 2; ++ns){
        const int o = (q*34 + ns*16 + ps)*8;
        bh[0][kc][ns] = *(const bf16x8*)&hs[(r0*2 + kc)*LROW + o];
        bh[1][kc][ns] = *(const bf16x8*)&hs[((SROWS + r0)*2 + kc)*LROW + o];
      }
  };
  auto mmx = [&](const bf16x8 (&ax)[4], const bf16x8 (&bx)[2][2]){
    __builtin_amdgcn_s_setprio(1);
#pragma unroll
    for (int ns = 0; ns < 2; ++ns)
#pragma unroll
      for (int g = 0; g < 4; ++g){
        acc[g][ns] = MFMA(ax[g], bx[0][ns], acc[g][ns]);
        acc[g][ns] = MFMA(ax[g], bx[1][ns], acc[g][ns]);
      }
    __builtin_amdgcn_s_setprio(0);
  };
  auto mmh = [&](const bf16x8 (&ah)[2][4], const bf16x8 (&bh)[2][2][2]){
    __builtin_amdgcn_s_setprio(1);
#pragma unroll
    for (int kc = 0; kc < 2; ++kc)
#pragma unroll
      for (int ns = 0; ns < 2; ++ns)
#pragma unroll
        for (int g = 0; g < 4; ++g){
          acc[g][ns] = MFMA(ah[kc][g], bh[0][kc][ns], acc[g][ns]);
          acc[g][ns] = MFMA(ah[kc][g], bh[1][kc][ns], acc[g][ns]);
        }
    __builtin_amdgcn_s_setprio(0);
  };

  // ---- double-buffered register sets (statically named, rule #20) ----
  bf16x8 ax0[4], ax1[4], ah0[2][4], ah1[2][4];
  bf16x8 bx0[2][2], bx1[2][2], bh0[2][2][2], bh1[2][2][2];
  loadwx(0, ax0); loadwx(1, ax1);
  if (!FIRST){ loadwh(0, ah0); loadwh(1, ah1); }

  __syncthreads();   // drains vmcnt(0): staging + weight + c loads complete

  ldx(0, bx0); if (!FIRST) ldh(0, bh0);

  // per tap T (cur set C, next set N):
  //   ldx(T+1,N)  -> mmx(C)  -> ldh(T+1,N) -> mmh(C) -> loadw(T+2 -> C)
  // next-tap LDS reads hide under current MFMAs; weight set C reloaded
  // only after its last use (mmh).
#define TAPSTEP(T, AXC, AHC, BXC, BHC, AXN, AHN, BXN, BHN)            \
  { if ((T) < 8) ldx((T)+1, BXN);                                     \
    mmx(AXC, BXC);                                                    \
    if (!FIRST && (T) < 8) ldh((T)+1, BHN);                           \
    if (!FIRST) mmh(AHC, BHC);                                        \
    if ((T) + 2 <= 8){ loadwx((T)+2, AXC); if (!FIRST) loadwh((T)+2, AHC); } }

  TAPSTEP(0, ax0,ah0,bx0,bh0, ax1,ah1,bx1,bh1)
  TAPSTEP(1, ax1,ah1,bx1,bh1, ax0,ah0,bx0,bh0)
  TAPSTEP(2, ax0,ah0,bx0,bh0, ax1,ah1,bx1,bh1)
  TAPSTEP(3, ax1,ah1,bx1,bh1, ax0,ah0,bx0,bh0)
  TAPSTEP(4, ax0,ah0,bx0,bh0, ax1,ah1,bx1,bh1)
  TAPSTEP(5, ax1,ah1,bx1,bh1, ax0,ah0,bx0,bh0)
  TAPSTEP(6, ax0,ah0,bx0,bh0, ax1,ah1,bx1,bh1)
  TAPSTEP(7, ax1,ah1,bx1,bh1, ax0,ah0,bx0,bh0)
  TAPSTEP(8, ax0,ah0,bx0,bh0, ax1,ah1,bx1,bh1)
#undef TAPSTEP

  // ---- epilogue: LSTM update, register-local ----
  // D layout: col = lane&15 = n (x), row = q*4 + r (hid within chunk)
  f32x4 bv[4];
#pragma unroll
  for (int g = 0; g < 4; ++g){
    f32x4 ba = *(const f32x4*)&bxb[g*HID + m0 + 4*q];
    f32x4 bb = *(const f32x4*)&bhb[g*HID + m0 + 4*q];
    bv[g] = ba + bb;
  }
  const int kc  = chunk >> 1;                       // h-layout indices for this
  const int qh  = ((chunk & 1) << 1) | (q >> 1);    // lane's 4 hid values
  const int c8b = (q & 1) * 4;
#pragma unroll
  for (int ns = 0; ns < 2; ++ns){
    const int xg = xh*32 + ns*16 + nn;
    f32x4 cn;
    float hn[4];
#pragma unroll
    for (int r = 0; r < 4; ++r){
      float iv = sigmoidf_(acc[0][ns][r] + bv[0][r]);
      float fv = sigmoidf_(acc[1][ns][r] + bv[1][r]);
      float gv = tanhf_  (acc[2][ns][r] + bv[2][r]);
      float ov = sigmoidf_(acc[3][ns][r] + bv[3][r]);
      float cnv = fv*cpre[ns][r] + iv*gv;
      cn[r] = cnv;
      hn[r] = ov * tanhf_(cnv);
    }
    *(f32x4*)&c_state[cslot + ns*4] = cn;
#pragma unroll
    for (int r = 0; r < 4; ++r)
      h_out[(((size_t)b*HID + m0 + 4*q + r)*HW + y)*HW + xg] = hn[r];
    const size_t hoff = ((size_t)b*PW + (y+1))*HROW + (kc*4 + qh)*QS + (xg+1)*8 + c8b;
    u16x4 ph, pl;
#pragma unroll
    for (int r = 0; r < 4; ++r){
      unsigned short h = f2bf(hn[r]);
      ph[r] = h;
      pl[r] = f2bf(hn[r] - bf2f(h));
    }
    *(u16x4*)&hch[hoff] = ph;
    *(u16x4*)&hcl[hoff] = pl;
  }
}

// ---------------- fallback: fp32 kernel (verified round 3) ----------------

#define FCHUNK  8
#define FTILE_H 16
#define FROWS   (FTILE_H + 2)
#define FSTRIDE 68

__device__ __forceinline__ void do_chunk_f(
    float tile[FCHUNK][FROWS][FSTRIDE],
    const float* __restrict__ src,
    const float* __restrict__ wp0, const float* __restrict__ wp1,
    const float* __restrict__ wp2, const float* __restrict__ wp3,
    int gy0, int txg, int ty, int tid, float (&acc)[4][2][4])
{
  __syncthreads();
  for (int s = tid; s < FCHUNK * FROWS * 32; s += 128) {
    int c2 = s & 31;
    int rowid = s >> 5;
    int ic = rowid / FROWS;
    int r  = rowid - ic * FROWS;
    int gy = gy0 - 1 + r;
    if ((unsigned)gy < (unsigned)HW) {
      float2 v = *(const float2*)&src[(ic << 12) + (gy << 6) + (c2 << 1)];
      *(float2*)&tile[ic][r][2 + (c2 << 1)] = v;
    }
  }
  __syncthreads();
  for (int ic = 0; ic < FCHUNK; ++ic) {
    float w0[9], w1[9], w2[9], w3[9];
#pragma unroll
    for (int k = 0; k < 9; ++k) {
      w0[k] = wp0[ic*9+k]; w1[k] = wp1[ic*9+k];
      w2[k] = wp2[ic*9+k]; w3[k] = wp3[ic*9+k];
    }
    float rv[4][8];
#pragma unroll
    for (int rr = 0; rr < 4; ++rr) {
      const float* p = &tile[ic][2*ty+rr][4*txg];
      float4 a  = *(const float4*)p;
      float4 bb = *(const float4*)(p + 4);
      rv[rr][0]=a.x; rv[rr][1]=a.y; rv[rr][2]=a.z; rv[rr][3]=a.w;
      rv[rr][4]=bb.x; rv[rr][5]=bb.y; rv[rr][6]=bb.z; rv[rr][7]=bb.w;
    }
#pragma unroll
    for (int j = 0; j < 2; ++j)
#pragma unroll
      for (int dy = 0; dy < 3; ++dy)
#pragma unroll
        for (int qq = 0; qq < 4; ++qq)
#pragma unroll
          for (int dx = 0; dx < 3; ++dx) {
            float v = rv[j+dy][qq+dx+1];
            int k = dy*3+dx;
            acc[0][j][qq] = fmaf(v, w0[k], acc[0][j][qq]);
            acc[1][j][qq] = fmaf(v, w1[k], acc[1][j][qq]);
            acc[2][j][qq] = fmaf(v, w2[k], acc[2][j][qq]);
            acc[3][j][qq] = fmaf(v, w3[k], acc[3][j][qq]);
          }
  }
}

__global__ __launch_bounds__(128) void convlstm_step_f(
    const float* __restrict__ x_t, const float* __restrict__ h_prev,
    const float* __restrict__ w_x2h, const float* __restrict__ b_x2h,
    const float* __restrict__ w_h2h, const float* __restrict__ b_h2h,
    float* __restrict__ c_state, float* __restrict__ h_out, int first)
{
  __shared__ float tile[FCHUNK][FROWS][FSTRIDE];
  const int txg = threadIdx.x, ty = threadIdx.y;
  const int tid = ty*16 + txg;
  const int by = blockIdx.x, hc = blockIdx.y, b = blockIdx.z;
  const int gy0 = by * FTILE_H;
  {
    float2* p = (float2*)&tile[0][0][0];
    for (int i = tid; i < FCHUNK*FROWS*FSTRIDE/2; i += 128)
      p[i] = make_float2(0.f, 0.f);
  }
  float acc[4][2][4];
#pragma unroll
  for (int g = 0; g < 4; ++g)
#pragma unroll
    for (int j = 0; j < 2; ++j)
#pragma unroll
      for (int qq = 0; qq < 4; ++qq) acc[g][j][qq] = 0.f;
  {
    const float* wx0 = w_x2h + (size_t)(0*HID+hc)*CX*9;
    const float* wx1 = w_x2h + (size_t)(1*HID+hc)*CX*9;
    const float* wx2 = w_x2h + (size_t)(2*HID+hc)*CX*9;
    const float* wx3 = w_x2h + (size_t)(3*HID+hc)*CX*9;
    for (int c0 = 0; c0 < CX; c0 += FCHUNK)
      do_chunk_f(tile, x_t + ((size_t)(b*CX+c0) << 12),
                 wx0+c0*9, wx1+c0*9, wx2+c0*9, wx3+c0*9, gy0, txg, ty, tid, acc);
  }
  if (!first){
    const float* wh0 = w_h2h + (size_t)(0*HID+hc)*HID*9;
    const float* wh1 = w_h2h + (size_t)(1*HID+hc)*HID*9;
    const float* wh2 = w_h2h + (size_t)(2*HID+hc)*HID*9;
    const float* wh3 = w_h2h + (size_t)(3*HID+hc)*HID*9;
    for (int c0 = 0; c0 < HID; c0 += FCHUNK)
      do_chunk_f(tile, h_prev + ((size_t)(b*HID+c0) << 12),
                 wh0+c0*9, wh1+c0*9, wh2+c0*9, wh3+c0*9, gy0, txg, ty, tid, acc);
  }
  const float bi = b_x2h[0*HID+hc] + b_h2h[0*HID+hc];
  const float bf = b_x2h[1*HID+hc] + b_h2h[1*HID+hc];
  const float bg = b_x2h[2*HID+hc] + b_h2h[2*HID+hc];
  const float bo = b_x2h[3*HID+hc] + b_h2h[3*HID+hc];
#pragma unroll
  for (int j = 0; j < 2; ++j){
    const int row = gy0 + 2*ty + j;
    const int off = ((b*HID + hc)*HW + row)*HW + 4*txg;
    float4 cpv4 = make_float4(0.f,0.f,0.f,0.f);
    if (!first) cpv4 = *(const float4*)&c_state[off];
    float cn[4], hn[4];
    const float cpv[4] = {cpv4.x, cpv4.y, cpv4.z, cpv4.w};
#pragma unroll
    for (int qq = 0; qq < 4; ++qq){
      const float ig = sigmoidf_(acc[0][j][qq] + bi);
      const float fg = sigmoidf_(acc[1][j][qq] + bf);
      const float gg = tanhf_  (acc[2][j][qq] + bg);
      const float og = sigmoidf_(acc[3][j][qq] + bo);
      const float cnv = fg*cpv[qq] + ig*gg;
      cn[qq] = cnv;
      hn[qq] = og * tanhf_(cnv);
    }
    *(float4*)&c_state[off] = make_float4(cn[0],cn[1],cn[2],cn[3]);
    *(float4*)&h_out[off]   = make_float4(hn[0],hn[1],hn[2],hn[3]);
  }
}

// ---------------- launcher ----------------

extern "C" void kernel_launch(void* const* d_in, const int* in_sizes, int n_in,
                              void* d_out, int out_size, void* d_ws, size_t ws_size,
                              hipStream_t stream) {
  const float* x     = (const float*)d_in[0];
  const float* w_x2h = (const float*)d_in[1];
  const float* b_x2h = (const float*)d_in[2];
  const float* w_h2h = (const float*)d_in[3];
  const float* b_h2h = (const float*)d_in[4];
  float* out = (float*)d_out;

  // ws layout (256-aligned)
  size_t off = 0;
  auto alloc = [&](size_t bytes) -> char* {
    char* p = (char*)d_ws + off;
    off += (bytes + 255) & ~(size_t)255;
    return p;
  };
  float* c_state = (float*)alloc((size_t)512*256*8*4);                // 4 MB
  unsigned short* wxT = (unsigned short*)alloc((size_t)9*4*2048*2);   // 147 KB
  unsigned short* whT = (unsigned short*)alloc((size_t)9*4*4096*2);   // 295 KB
  const size_t hT_bytes = (size_t)BATCH*PW*HROW*2;                    // 2,230,272
  unsigned short* hA_hi = (unsigned short*)alloc(hT_bytes);
  unsigned short* hA_lo = (unsigned short*)alloc(hT_bytes);
  unsigned short* hB_hi = (unsigned short*)alloc(hT_bytes);
  unsigned short* hB_lo = (unsigned short*)alloc(hT_bytes);
  const size_t xT_bytes = (size_t)TSTEPS*BATCH*PW*XROW*2;             // 17,842,176
  unsigned short* xT_hi = (unsigned short*)alloc(xT_bytes);
  unsigned short* xT_lo = (unsigned short*)alloc(xT_bytes);
  const size_t need = off;

  const size_t x_step = (size_t)BATCH*CX*HW*HW;
  const size_t h_step = (size_t)BATCH*HID*HW*HW;

  if (need <= ws_size) {
    // ---- MFMA path ----
    prep_w<<<(9*256*HID + 255)/256, 256, 0, stream>>>(w_x2h, w_h2h, wxT, whT);
    prep_x<<<dim3(TSTEPS*BATCH, PW), 256, 0, stream>>>(x, xT_hi, xT_lo);
    zero_ws<<<1024, 256, 0, stream>>>((unsigned long long*)hA_hi, 4*hT_bytes/8);

    for (int t = 0; t < TSTEPS; ++t) {
      unsigned short* hp_hi = (t & 1) ? hA_hi : hB_hi;
      unsigned short* hp_lo = (t & 1) ? hA_lo : hB_lo;
      unsigned short* hc_hi = (t & 1) ? hB_hi : hA_hi;
      unsigned short* hc_lo = (t & 1) ? hB_lo : hA_lo;
      if (t == 0)
        step_mfma<1><<<dim3(8, 16, BATCH), 256, 0, stream>>>(
            xT_hi, xT_lo, wxT, whT, hp_hi, hp_lo, hc_hi, hc_lo,
            b_x2h, b_h2h, c_state, out + (size_t)t*h_step, t);
      else
        step_mfma<0><<<dim3(8, 16, BATCH), 256, 0, stream>>>(
            xT_hi, xT_lo, wxT, whT, hp_hi, hp_lo, hc_hi, hc_lo,
            b_x2h, b_h2h, c_state, out + (size_t)t*h_step, t);
    }
  } else {
    // ---- fallback fp32 path ----
    dim3 grid(HW / FTILE_H, HID, BATCH);
    dim3 block(16, 8);
    for (int t = 0; t < TSTEPS; ++t) {
      const float* x_t    = x + (size_t)t*x_step;
      const float* h_prev = (t == 0) ? x : out + (size_t)(t-1)*h_step;
      float* h_out        = out + (size_t)t*h_step;
      convlstm_step_f<<<grid, block, 0, stream>>>(
          x_t, h_prev, w_x2h, b_x2h, w_h2h, b_h2h, c_state, h_out, t == 0 ? 1 : 0);
    }
  }
}